// Round 1
// baseline (567.644 us; speedup 1.0000x reference)
//
#include <hip/hip_runtime.h>
#include <hip/hip_bf16.h>

// Problem: B=2, S=4096, D=768, H=12, d_head=64.
// qkv = x @ W_in + b_in; causal MHA; out = y @ W_out + b_out.
// Strategy: bf16 MFMA (16x16x32) everywhere, fp32 accumulate, bf16 intermediates in ws.

#define D_MODEL 768
#define SEQ 4096
#define NB 2
#define NHEAD 12

typedef __attribute__((ext_vector_type(8))) short short8;
typedef __attribute__((ext_vector_type(4))) float floatx4;

__device__ inline short f2bf(float f) {
    unsigned u = __builtin_bit_cast(unsigned, f);
    u += 0x7fff + ((u >> 16) & 1);   // round-to-nearest-even
    return (short)(u >> 16);
}

// ---------------------------------------------------------------------------
// GEMM: C[M][N] = A[M][K] @ B[K][N] (+ bias[N]).
// A is fp32 or bf16 (template), B fp32, C bf16 or fp32 (template).
// 64x64 tile, BK=32, 256 threads = 4 waves in 2x2; each wave computes a 32x32
// quadrant as 2x2 MFMA fragments. LDS layouts are [m][k] and [n][k] so every
// fragment load is one contiguous 16B read.
// ---------------------------------------------------------------------------
template <bool A_IS_BF16, bool OUT_BF16>
__global__ __launch_bounds__(256) void gemm_k(const void* __restrict__ Ap,
                                              const float* __restrict__ B,
                                              const float* __restrict__ bias,
                                              void* __restrict__ Cp,
                                              int M, int N, int K) {
    __shared__ short As[64][32];   // [m][k] bf16
    __shared__ short Bt[64][32];   // [n][k] bf16 (B transposed)

    const int tid  = threadIdx.x;
    const int lane = tid & 63;
    const int wid  = tid >> 6;
    const int wr   = wid >> 1, wc = wid & 1;     // 2x2 wave grid
    const int lo   = lane & 15, hi = lane >> 4;  // fragment coords
    const int m0   = blockIdx.y * 64, n0 = blockIdx.x * 64;

    floatx4 acc[2][2] = {};

    for (int k0 = 0; k0 < K; k0 += 32) {
        __syncthreads();
        // ---- stage A tile (64x32): thread t loads 8 contiguous elems.
        {
            int row = tid >> 2, col = (tid & 3) * 8;
            if constexpr (A_IS_BF16) {
                const short* s = (const short*)Ap + (size_t)(m0 + row) * K + k0 + col;
                *(short8*)&As[row][col] = *(const short8*)s;
            } else {
                const float* s = (const float*)Ap + (size_t)(m0 + row) * K + k0 + col;
                float4 f0 = *(const float4*)(s);
                float4 f1 = *(const float4*)(s + 4);
                short tmp[8] = {f2bf(f0.x), f2bf(f0.y), f2bf(f0.z), f2bf(f0.w),
                                f2bf(f1.x), f2bf(f1.y), f2bf(f1.z), f2bf(f1.w)};
                *(short8*)&As[row][col] = *(const short8*)tmp;
            }
        }
        // ---- stage B tile (32x64) transposed into Bt[n][k].
        {
            int kk = tid >> 3, nn0 = (tid & 7) * 8;
            const float* s = B + (size_t)(k0 + kk) * N + n0 + nn0;
            float4 f0 = *(const float4*)(s);
            float4 f1 = *(const float4*)(s + 4);
            float fv[8] = {f0.x, f0.y, f0.z, f0.w, f1.x, f1.y, f1.z, f1.w};
#pragma unroll
            for (int i = 0; i < 8; ++i) Bt[nn0 + i][kk] = f2bf(fv[i]);
        }
        __syncthreads();
        // ---- MFMA: K=32 covered by one instruction per fragment pair.
#pragma unroll
        for (int mf = 0; mf < 2; ++mf) {
            short8 a = *(const short8*)&As[wr * 32 + mf * 16 + lo][hi * 8];
#pragma unroll
            for (int nf = 0; nf < 2; ++nf) {
                short8 b = *(const short8*)&Bt[wc * 32 + nf * 16 + lo][hi * 8];
                acc[mf][nf] = __builtin_amdgcn_mfma_f32_16x16x32_bf16(a, b, acc[mf][nf], 0, 0, 0);
            }
        }
    }

    // ---- epilogue: D layout col=lane&15, row=(lane>>4)*4+reg  (verified m89/m91)
#pragma unroll
    for (int mf = 0; mf < 2; ++mf)
#pragma unroll
        for (int nf = 0; nf < 2; ++nf)
#pragma unroll
            for (int r = 0; r < 4; ++r) {
                int row = m0 + wr * 32 + mf * 16 + hi * 4 + r;
                int col = n0 + wc * 32 + nf * 16 + lo;
                float v = acc[mf][nf][r] + (bias ? bias[col] : 0.0f);
                if constexpr (OUT_BF16)
                    ((short*)Cp)[(size_t)row * N + col] = f2bf(v);
                else
                    ((float*)Cp)[(size_t)row * N + col] = v;
            }
}

// ---------------------------------------------------------------------------
// Flash attention (causal). qkv bf16 [B][S][2304]; y bf16 [B][S][768].
// 1 block = (b, h, q-tile of 64). 4 waves, each owns 16 q-rows.
// Q in registers; K staged [key][d]; V staged transposed [d][key]; P via LDS.
// ---------------------------------------------------------------------------
__global__ __launch_bounds__(256) void attn_k(const short* __restrict__ qkv,
                                              short* __restrict__ y) {
    const int qt = blockIdx.x, h = blockIdx.y, b = blockIdx.z;
    const int tid = threadIdx.x, lane = tid & 63, w = tid >> 6;
    const int lo = lane & 15, hi = lane >> 4;
    const int ld = 3 * D_MODEL;

    const short* base = qkv + (size_t)b * SEQ * ld;
    const short* qp = base + h * 64;
    const short* kp = base + D_MODEL + h * 64;
    const short* vp = base + 2 * D_MODEL + h * 64;

    __shared__ short Ks[64][72];  // [key][d]   (pad 72: 144B rows, 16B aligned)
    __shared__ short Vt[64][72];  // [d][key]
    __shared__ short Ps[64][72];  // [qrow][key]

    const int q0 = qt * 64;

    // Q fragments: row = q0 + w*16 + lo, dims kc*32 + hi*8 + i
    short8 qf[2];
    {
        const short* src = qp + (size_t)(q0 + w * 16 + lo) * ld + hi * 8;
        qf[0] = *(const short8*)(src);
        qf[1] = *(const short8*)(src + 32);
    }

    floatx4 o[4] = {};           // O[dimchunk][reg]: row=hi*4+reg, dim=dc*16+lo
    float mrun[4], lrun[4];
#pragma unroll
    for (int r = 0; r < 4; ++r) { mrun[r] = -1e30f; lrun[r] = 0.0f; }

    for (int kb = 0; kb <= qt; ++kb) {
        const int k0 = kb * 64;
        __syncthreads();
        // ---- stage K [key][d] and V transposed [d][key]; thread: key=tid/4, 16 dims
        {
            int key = tid >> 2, d0 = (tid & 3) * 16;
            const short* ks = kp + (size_t)(k0 + key) * ld + d0;
            *(short8*)&Ks[key][d0]     = *(const short8*)(ks);
            *(short8*)&Ks[key][d0 + 8] = *(const short8*)(ks + 8);
            const short* vs = vp + (size_t)(k0 + key) * ld + d0;
            short tv[16];
            *(short8*)&tv[0] = *(const short8*)(vs);
            *(short8*)&tv[8] = *(const short8*)(vs + 8);
#pragma unroll
            for (int i = 0; i < 16; ++i) Vt[d0 + i][key] = tv[i];
        }
        __syncthreads();

        // ---- S = Q K^T * 0.125 : 4 key-chunks of 16
        floatx4 s[4];
#pragma unroll
        for (int c = 0; c < 4; ++c) {
            floatx4 a = {};
#pragma unroll
            for (int kc = 0; kc < 2; ++kc) {
                short8 bfr = *(const short8*)&Ks[c * 16 + lo][kc * 32 + hi * 8];
                a = __builtin_amdgcn_mfma_f32_16x16x32_bf16(qf[kc], bfr, a, 0, 0, 0);
            }
            s[c] = a;
        }

        // ---- online softmax (per q-row; row r lives on 16 lanes of this group)
        const bool diag = (kb == qt);
        float pv[4][4];  // [c][r]
#pragma unroll
        for (int r = 0; r < 4; ++r) {
            int qrow = w * 16 + hi * 4 + r;  // within tile
            float mx = -1e30f;
#pragma unroll
            for (int c = 0; c < 4; ++c) {
                float val = s[c][r] * 0.125f;
                if (diag && (c * 16 + lo) > qrow) val = -1e30f;
                pv[c][r] = val;
                mx = fmaxf(mx, val);
            }
#pragma unroll
            for (int off = 1; off < 16; off <<= 1)
                mx = fmaxf(mx, __shfl_xor(mx, off, 64));

            float mnew  = fmaxf(mrun[r], mx);
            float scale = __expf(mrun[r] - mnew);
            mrun[r] = mnew;
            float rs = 0.0f;
#pragma unroll
            for (int c = 0; c < 4; ++c) {
                float p = __expf(pv[c][r] - mnew);
                pv[c][r] = p;
                rs += p;
            }
#pragma unroll
            for (int off = 1; off < 16; off <<= 1) rs += __shfl_xor(rs, off, 64);
            lrun[r] = lrun[r] * scale + rs;
#pragma unroll
            for (int dc = 0; dc < 4; ++dc) o[dc][r] *= scale;
#pragma unroll
            for (int c = 0; c < 4; ++c)
                Ps[w * 16 + hi * 4 + r][c * 16 + lo] = f2bf(pv[c][r]);
        }

        // wave-local LDS produce->consume: drain lgkm, wave lockstep covers lanes
        asm volatile("s_waitcnt lgkmcnt(0)" ::: "memory");

        // ---- O += P V
#pragma unroll
        for (int kc = 0; kc < 2; ++kc) {
            short8 pa = *(const short8*)&Ps[w * 16 + lo][kc * 32 + hi * 8];
#pragma unroll
            for (int dc = 0; dc < 4; ++dc) {
                short8 vb = *(const short8*)&Vt[dc * 16 + lo][kc * 32 + hi * 8];
                o[dc] = __builtin_amdgcn_mfma_f32_16x16x32_bf16(pa, vb, o[dc], 0, 0, 0);
            }
        }
    }

    // ---- finalize: y[b][row][h*64 + dim] = O / l
#pragma unroll
    for (int r = 0; r < 4; ++r) {
        float inv = 1.0f / lrun[r];
        int row = q0 + w * 16 + hi * 4 + r;
        short* dst = y + ((size_t)b * SEQ + row) * D_MODEL + h * 64;
#pragma unroll
        for (int dc = 0; dc < 4; ++dc)
            dst[dc * 16 + lo] = f2bf(o[dc][r] * inv);
    }
}

extern "C" void kernel_launch(void* const* d_in, const int* in_sizes, int n_in,
                              void* d_out, int out_size, void* d_ws, size_t ws_size,
                              hipStream_t stream) {
    (void)in_sizes; (void)n_in; (void)out_size; (void)ws_size;
    const float* x     = (const float*)d_in[0];
    const float* W_in  = (const float*)d_in[1];
    const float* b_in  = (const float*)d_in[2];
    const float* W_out = (const float*)d_in[3];
    const float* b_out = (const float*)d_in[4];
    float* out = (float*)d_out;

    const int M = NB * SEQ;          // 8192
    short* qkv_ws = (short*)d_ws;                                     // 8192*2304 bf16
    short* y_ws   = (short*)((char*)d_ws + (size_t)M * 3 * D_MODEL * 2); // 8192*768 bf16

    dim3 blk(256);
    // 1) qkv = x @ W_in + b_in   -> bf16
    gemm_k<false, true><<<dim3((3 * D_MODEL) / 64, M / 64), blk, 0, stream>>>(
        (const void*)x, W_in, b_in, (void*)qkv_ws, M, 3 * D_MODEL, D_MODEL);
    // 2) causal attention -> y bf16
    attn_k<<<dim3(SEQ / 64, NHEAD, NB), blk, 0, stream>>>(qkv_ws, y_ws);
    // 3) out = y @ W_out + b_out -> fp32
    gemm_k<true, false><<<dim3(D_MODEL / 64, M / 64), blk, 0, stream>>>(
        (const void*)y_ws, W_out, b_out, (void*)out, M, D_MODEL, D_MODEL);
}

// Round 2
// 381.720 us; speedup vs baseline: 1.4871x; 1.4871x over previous
//
#include <hip/hip_runtime.h>
#include <hip/hip_bf16.h>

// B=2, S=4096, D=768, H=12, d_head=64.
// qkv = x @ W_in + b_in; causal MHA; out = y @ W_out + b_out.
// bf16 MFMA 16x16x32 everywhere, fp32 accumulate, bf16 intermediates in ws.
// ws layout: qk_ws [b][s][1536] (Q|K), vt_ws [b][h][64][4096] (V transposed),
//            y_ws [8192][768].

#define D_MODEL 768
#define SEQ 4096
#define NB 2
#define NHEAD 12
#define LDQK 1536

typedef __attribute__((ext_vector_type(8))) short short8;
typedef __attribute__((ext_vector_type(4))) short short4v;
typedef __attribute__((ext_vector_type(4))) float floatx4;

__device__ inline short f2bf(float f) {
    unsigned u = __builtin_bit_cast(unsigned, f);
    u += 0x7fff + ((u >> 16) & 1);   // round-to-nearest-even
    return (short)(u >> 16);
}
__device__ inline unsigned pack2(float a, float b) {
    return (unsigned)(unsigned short)f2bf(a) | ((unsigned)(unsigned short)f2bf(b) << 16);
}

// ---------------------------------------------------------------------------
// QKV GEMM: qkv = x @ W_in + b_in. M=8192, N=2304, K=768.
// cols < 1536 -> qk_ws[row][col] (stride 1536)
// cols >=1536 -> vt_ws[b][h][dh][s]  (V stored transposed; lane's 4 acc rows
//               are 4 consecutive s -> one 8B store)
// ---------------------------------------------------------------------------
__global__ __launch_bounds__(256) void gemm_qkv(const float* __restrict__ A,
                                                const float* __restrict__ B,
                                                const float* __restrict__ bias,
                                                short* __restrict__ qk,
                                                short* __restrict__ vt) {
    const int M = NB * SEQ, N = 3 * D_MODEL, K = D_MODEL;
    __shared__ short As[64][32];   // [m][k]
    __shared__ short Bt[64][32];   // [n][k]

    const int tid  = threadIdx.x;
    const int lane = tid & 63;
    const int wid  = tid >> 6;
    const int wr   = wid >> 1, wc = wid & 1;
    const int lo   = lane & 15, hi = lane >> 4;
    const int m0   = blockIdx.y * 64, n0 = blockIdx.x * 64;
    (void)M;

    floatx4 acc[2][2] = {};

    for (int k0 = 0; k0 < K; k0 += 32) {
        __syncthreads();
        {   // stage A (fp32 -> bf16)
            int row = tid >> 2, col = (tid & 3) * 8;
            const float* s = A + (size_t)(m0 + row) * K + k0 + col;
            float4 f0 = *(const float4*)(s);
            float4 f1 = *(const float4*)(s + 4);
            short tmp[8] = {f2bf(f0.x), f2bf(f0.y), f2bf(f0.z), f2bf(f0.w),
                            f2bf(f1.x), f2bf(f1.y), f2bf(f1.z), f2bf(f1.w)};
            *(short8*)&As[row][col] = *(const short8*)tmp;
        }
        {   // stage B transposed
            int kk = tid >> 3, nn0 = (tid & 7) * 8;
            const float* s = B + (size_t)(k0 + kk) * N + n0 + nn0;
            float4 f0 = *(const float4*)(s);
            float4 f1 = *(const float4*)(s + 4);
            float fv[8] = {f0.x, f0.y, f0.z, f0.w, f1.x, f1.y, f1.z, f1.w};
#pragma unroll
            for (int i = 0; i < 8; ++i) Bt[nn0 + i][kk] = f2bf(fv[i]);
        }
        __syncthreads();
#pragma unroll
        for (int mf = 0; mf < 2; ++mf) {
            short8 a = *(const short8*)&As[wr * 32 + mf * 16 + lo][hi * 8];
#pragma unroll
            for (int nf = 0; nf < 2; ++nf) {
                short8 b = *(const short8*)&Bt[wc * 32 + nf * 16 + lo][hi * 8];
                acc[mf][nf] = __builtin_amdgcn_mfma_f32_16x16x32_bf16(a, b, acc[mf][nf], 0, 0, 0);
            }
        }
    }

#pragma unroll
    for (int mf = 0; mf < 2; ++mf)
#pragma unroll
        for (int nf = 0; nf < 2; ++nf) {
            int col  = n0 + wc * 32 + nf * 16 + lo;
            int row0 = m0 + wr * 32 + mf * 16 + hi * 4;
            float bv = bias[col];
            if (col < LDQK) {
#pragma unroll
                for (int r = 0; r < 4; ++r)
                    qk[(size_t)(row0 + r) * LDQK + col] = f2bf(acc[mf][nf][r] + bv);
            } else {
                int vcol = col - LDQK;
                int h = vcol >> 6, dh = vcol & 63;
                int bb = row0 >> 12, s = row0 & 4095;
                short tmp[4] = {f2bf(acc[mf][nf][0] + bv), f2bf(acc[mf][nf][1] + bv),
                                f2bf(acc[mf][nf][2] + bv), f2bf(acc[mf][nf][3] + bv)};
                *(short4v*)&vt[(((size_t)bb * NHEAD + h) * 64 + dh) * SEQ + s] = *(const short4v*)tmp;
            }
        }
}

// ---------------------------------------------------------------------------
// Out GEMM: out = y @ W_out + b_out. A bf16 [8192][768], out fp32.
// ---------------------------------------------------------------------------
__global__ __launch_bounds__(256) void gemm_out(const short* __restrict__ Ap,
                                                const float* __restrict__ B,
                                                const float* __restrict__ bias,
                                                float* __restrict__ Cp,
                                                int M, int N, int K) {
    __shared__ short As[64][32];
    __shared__ short Bt[64][32];

    const int tid  = threadIdx.x;
    const int lane = tid & 63;
    const int wid  = tid >> 6;
    const int wr   = wid >> 1, wc = wid & 1;
    const int lo   = lane & 15, hi = lane >> 4;
    const int m0   = blockIdx.y * 64, n0 = blockIdx.x * 64;

    floatx4 acc[2][2] = {};

    for (int k0 = 0; k0 < K; k0 += 32) {
        __syncthreads();
        {
            int row = tid >> 2, col = (tid & 3) * 8;
            const short* s = Ap + (size_t)(m0 + row) * K + k0 + col;
            *(short8*)&As[row][col] = *(const short8*)s;
        }
        {
            int kk = tid >> 3, nn0 = (tid & 7) * 8;
            const float* s = B + (size_t)(k0 + kk) * N + n0 + nn0;
            float4 f0 = *(const float4*)(s);
            float4 f1 = *(const float4*)(s + 4);
            float fv[8] = {f0.x, f0.y, f0.z, f0.w, f1.x, f1.y, f1.z, f1.w};
#pragma unroll
            for (int i = 0; i < 8; ++i) Bt[nn0 + i][kk] = f2bf(fv[i]);
        }
        __syncthreads();
#pragma unroll
        for (int mf = 0; mf < 2; ++mf) {
            short8 a = *(const short8*)&As[wr * 32 + mf * 16 + lo][hi * 8];
#pragma unroll
            for (int nf = 0; nf < 2; ++nf) {
                short8 b = *(const short8*)&Bt[wc * 32 + nf * 16 + lo][hi * 8];
                acc[mf][nf] = __builtin_amdgcn_mfma_f32_16x16x32_bf16(a, b, acc[mf][nf], 0, 0, 0);
            }
        }
    }

#pragma unroll
    for (int mf = 0; mf < 2; ++mf)
#pragma unroll
        for (int nf = 0; nf < 2; ++nf)
#pragma unroll
            for (int r = 0; r < 4; ++r) {
                int row = m0 + wr * 32 + mf * 16 + hi * 4 + r;
                int col = n0 + wc * 32 + nf * 16 + lo;
                Cp[(size_t)row * N + col] = acc[mf][nf][r] + bias[col];
            }
}

// ---------------------------------------------------------------------------
// Flash attention (causal), swapped-QK^T + in-register softmax.
// Block = (qtile 64, h, b); 4 waves; wave w owns q rows w*16..w*16+15.
// Per lane: q-col = lane&15; S^T[key][q] from mfma(K,Q); full key-row is
// lane-local -> softmax = in-lane max/sum + 2 shfl_xor. P goes through a
// WAVE-LOCAL LDS region (no barrier) to become the PV A-fragment.
// All LDS XOR-swizzled to bank floor (T2).
// ---------------------------------------------------------------------------
__global__ __launch_bounds__(256) void attn_k(const short* __restrict__ qk,
                                              const short* __restrict__ vt,
                                              short* __restrict__ y) {
    const int qt = blockIdx.x, h = blockIdx.y, b = blockIdx.z;
    const int tid = threadIdx.x, lane = tid & 63, w = tid >> 6;
    const int lo = lane & 15, hi = lane >> 4;

    __shared__ alignas(16) short Ks[64 * 64];   // addr(key,dblk) = key*64 + (dblk^(key&7))*8
    __shared__ alignas(16) short Vs[64 * 64];   // addr(dim,kblk) = dim*64 + (kblk^(dim&7))*8
    __shared__ alignas(16) short Ps[4 * 16 * 64]; // per-wave 1024 shorts; 4-short blocks ^ (q&14)

    const int q0 = qt * 64;
    const short* qbase = qk + (size_t)b * SEQ * LDQK;
    const short* kbase = qbase + D_MODEL;
    const short* vbase = vt + ((size_t)b * NHEAD + h) * 64 * SEQ;

    // Q fragments (B-operand): lane holds q = q0 + w*16 + lo, dims kc*32+hi*8..
    short8 qf[2];
    {
        const short* qrow = qbase + (size_t)(q0 + w * 16 + lo) * LDQK + h * 64;
        qf[0] = *(const short8*)(qrow + hi * 8);
        qf[1] = *(const short8*)(qrow + 32 + hi * 8);
    }

    floatx4 o[4] = {};                 // O[q=hi*4+r][dim=dc*16+lo]
    float mrun = -1e30f, lrun = 0.0f;  // softmax state for q = w*16+lo

    const int skey = tid >> 2, sdc = tid & 3;  // K staging: 1 key row, 16 dims
    const int sdim = tid >> 2, skg = tid & 3;  // V staging: 1 dim row, 16 keys

    short8 kpre[2], vpre[2];
    {
        const short* ksrc = kbase + (size_t)skey * LDQK + h * 64 + sdc * 16;
        kpre[0] = *(const short8*)ksrc;
        kpre[1] = *(const short8*)(ksrc + 8);
        const short* vsrc = vbase + (size_t)sdim * SEQ + skg * 16;
        vpre[0] = *(const short8*)vsrc;
        vpre[1] = *(const short8*)(vsrc + 8);
    }

    float sc4[4];
    for (int kb = 0; kb <= qt; ++kb) {
        __syncthreads();
        {   // commit staged tile (vector writes, swizzled -> bank floor)
            int kb0 = sdc * 2;
            *(short8*)&Ks[skey * 64 + ((kb0    ) ^ (skey & 7)) * 8] = kpre[0];
            *(short8*)&Ks[skey * 64 + ((kb0 + 1) ^ (skey & 7)) * 8] = kpre[1];
            int vb0 = skg * 2;
            *(short8*)&Vs[sdim * 64 + ((vb0    ) ^ (sdim & 7)) * 8] = vpre[0];
            *(short8*)&Vs[sdim * 64 + ((vb0 + 1) ^ (sdim & 7)) * 8] = vpre[1];
        }
        __syncthreads();
        if (kb < qt) {  // async-STAGE split: issue next tile's loads before compute
            int k0n = (kb + 1) * 64;
            const short* ksrc = kbase + (size_t)(k0n + skey) * LDQK + h * 64 + sdc * 16;
            kpre[0] = *(const short8*)ksrc;
            kpre[1] = *(const short8*)(ksrc + 8);
            const short* vsrc = vbase + (size_t)sdim * SEQ + k0n + skg * 16;
            vpre[0] = *(const short8*)vsrc;
            vpre[1] = *(const short8*)(vsrc + 8);
        }

        // ---- S^T = K @ Q^T : lane holds S[key=c*16+hi*4+r][q=w*16+lo]
        floatx4 sT[4];
#pragma unroll
        for (int c = 0; c < 4; ++c) {
            floatx4 acc = {};
#pragma unroll
            for (int kc = 0; kc < 2; ++kc) {
                short8 kf = *(const short8*)&Ks[(c * 16 + lo) * 64 + ((kc * 4 + hi) ^ (lo & 7)) * 8];
                acc = __builtin_amdgcn_mfma_f32_16x16x32_bf16(kf, qf[kc], acc, 0, 0, 0);
            }
            sT[c] = acc;
        }

        // ---- softmax, fully in-register for q = w*16+lo
        float p[4][4];
        const bool diag = (kb == qt);
        const int qin = w * 16 + lo;
        float mx = -1e30f;
#pragma unroll
        for (int c = 0; c < 4; ++c)
#pragma unroll
            for (int r = 0; r < 4; ++r) {
                float v = sT[c][r] * 0.125f;
                if (diag && (c * 16 + hi * 4 + r) > qin) v = -1e30f;
                p[c][r] = v;
                mx = fmaxf(mx, v);
            }
        mx = fmaxf(mx, __shfl_xor(mx, 16, 64));
        mx = fmaxf(mx, __shfl_xor(mx, 32, 64));
        float mnew = fmaxf(mrun, mx);
        float sc = __expf(mrun - mnew);
        mrun = mnew;
        float rs = 0.0f;
#pragma unroll
        for (int c = 0; c < 4; ++c)
#pragma unroll
            for (int r = 0; r < 4; ++r) {
                float e = __expf(p[c][r] - mnew);
                p[c][r] = e;
                rs += e;
            }
        rs += __shfl_xor(rs, 16, 64);
        rs += __shfl_xor(rs, 32, 64);
        lrun = lrun * sc + rs;

        // O rows are q = hi*4+r -> fetch their scales from lanes lo = hi*4+r
#pragma unroll
        for (int r = 0; r < 4; ++r) sc4[r] = __shfl(sc, hi * 4 + r, 16);
#pragma unroll
        for (int dc = 0; dc < 4; ++dc)
#pragma unroll
            for (int r = 0; r < 4; ++r) o[dc][r] *= sc4[r];

        // ---- P^T -> wave-local LDS (packed u32, swizzled), no barrier needed
        unsigned* pw = (unsigned*)&Ps[w * 1024];
#pragma unroll
        for (int c = 0; c < 4; ++c)
#pragma unroll
            for (int rp = 0; rp < 2; ++rp) {
                unsigned word = pack2(p[c][rp * 2], p[c][rp * 2 + 1]);
                pw[(lo * 64 + (((c * 4 + hi) ^ (lo & 14)) * 4) + rp * 2) >> 1] = word;
            }
        asm volatile("s_waitcnt lgkmcnt(0)" ::: "memory");

        // ---- O += P V  (A = P rows from LDS, B = V^T rows from LDS)
#pragma unroll
        for (int kc = 0; kc < 2; ++kc) {
            short8 af = *(const short8*)&Ps[w * 1024 + lo * 64 + ((kc * 8 + hi * 2) ^ (lo & 14)) * 4];
#pragma unroll
            for (int dc = 0; dc < 4; ++dc) {
                short8 vf = *(const short8*)&Vs[(dc * 16 + lo) * 64 + ((kc * 4 + hi) ^ (lo & 7)) * 8];
                o[dc] = __builtin_amdgcn_mfma_f32_16x16x32_bf16(af, vf, o[dc], 0, 0, 0);
            }
        }
    }

    // ---- finalize: rows need 1/l for q = hi*4+r
#pragma unroll
    for (int r = 0; r < 4; ++r) sc4[r] = __shfl(lrun, hi * 4 + r, 16);
#pragma unroll
    for (int r = 0; r < 4; ++r) {
        float inv = 1.0f / sc4[r];
        int row = q0 + w * 16 + hi * 4 + r;
        short* dst = y + ((size_t)b * SEQ + row) * D_MODEL + h * 64;
#pragma unroll
        for (int dc = 0; dc < 4; ++dc) dst[dc * 16 + lo] = f2bf(o[dc][r] * inv);
    }
}

extern "C" void kernel_launch(void* const* d_in, const int* in_sizes, int n_in,
                              void* d_out, int out_size, void* d_ws, size_t ws_size,
                              hipStream_t stream) {
    (void)in_sizes; (void)n_in; (void)out_size; (void)ws_size;
    const float* x     = (const float*)d_in[0];
    const float* W_in  = (const float*)d_in[1];
    const float* b_in  = (const float*)d_in[2];
    const float* W_out = (const float*)d_in[3];
    const float* b_out = (const float*)d_in[4];
    float* out = (float*)d_out;

    const int M = NB * SEQ;  // 8192
    short* qk_ws = (short*)d_ws;                                        // 8192*1536 bf16
    short* vt_ws = (short*)((char*)d_ws + (size_t)M * LDQK * 2);        // 24*64*4096 bf16
    short* y_ws  = (short*)((char*)d_ws + (size_t)M * LDQK * 2
                                        + (size_t)NB * NHEAD * 64 * SEQ * 2);  // 8192*768 bf16

    dim3 blk(256);
    gemm_qkv<<<dim3((3 * D_MODEL) / 64, M / 64), blk, 0, stream>>>(x, W_in, b_in, qk_ws, vt_ws);
    attn_k<<<dim3(SEQ / 64, NHEAD, NB), blk, 0, stream>>>(qk_ws, vt_ws, y_ws);
    gemm_out<<<dim3(D_MODEL / 64, M / 64), blk, 0, stream>>>(y_ws, W_out, b_out, out, M, D_MODEL, D_MODEL);
}

// Round 3
// 216.675 us; speedup vs baseline: 2.6198x; 1.7617x over previous
//
#include <hip/hip_runtime.h>
#include <hip/hip_bf16.h>

// B=2, S=4096, D=768, H=12, d_head=64.
// Pipeline: convert x/W to bf16 (W transposed) -> 128^2-tile MFMA GEMM with
// global_load_lds (m97 structure) -> balanced flash attention (paired q-tiles)
// -> 128^2 out GEMM.
// ws: x_bf[8192][768], wt_in[2304][768], wt_out[768][768],
//     qk[b][s][1536], vt[b][h][64][4096], y[8192][768]  (all bf16)

#define D_MODEL 768
#define SEQ 4096
#define NB 2
#define NHEAD 12
#define LDQK 1536

typedef __attribute__((ext_vector_type(8))) short short8;
typedef __attribute__((ext_vector_type(4))) short short4v;
typedef __attribute__((ext_vector_type(4))) float floatx4;

__device__ inline short f2bf(float f) {
    unsigned u = __builtin_bit_cast(unsigned, f);
    u += 0x7fff + ((u >> 16) & 1);   // RNE
    return (short)(u >> 16);
}
__device__ inline unsigned pack2(float a, float b) {
    return (unsigned)(unsigned short)f2bf(a) | ((unsigned)(unsigned short)f2bf(b) << 16);
}
__device__ inline void gload16(const void* g, void* l) {
    __builtin_amdgcn_global_load_lds(
        (const __attribute__((address_space(1))) unsigned int*)g,
        (__attribute__((address_space(3))) unsigned int*)l, 16, 0, 0);
}

// ---------------------------------------------------------------------------
// fp32 -> bf16 elementwise (n multiple of 2048)
// ---------------------------------------------------------------------------
__global__ __launch_bounds__(256) void convert_bf16(const float* __restrict__ src,
                                                    short* __restrict__ dst, size_t n) {
    size_t i = ((size_t)blockIdx.x * 256 + threadIdx.x) * 8;
    if (i >= n) return;
    float4 f0 = *(const float4*)(src + i);
    float4 f1 = *(const float4*)(src + i + 4);
    short t[8] = {f2bf(f0.x), f2bf(f0.y), f2bf(f0.z), f2bf(f0.w),
                  f2bf(f1.x), f2bf(f1.y), f2bf(f1.z), f2bf(f1.w)};
    *(short8*)(dst + i) = *(const short8*)t;
}

// ---------------------------------------------------------------------------
// W[K][N] fp32 -> Wt[N][K] bf16, 32x32 tiles. block (32,8).
// ---------------------------------------------------------------------------
__global__ __launch_bounds__(256) void transpose_bf16(const float* __restrict__ W,
                                                      short* __restrict__ Wt,
                                                      int K, int N) {
    __shared__ short t[32][33];
    const int n0 = blockIdx.x * 32, k0 = blockIdx.y * 32;
    const int tx = threadIdx.x, ty = threadIdx.y;
#pragma unroll
    for (int j = 0; j < 4; ++j)
        t[ty + j * 8][tx] = f2bf(W[(size_t)(k0 + ty + j * 8) * N + n0 + tx]);
    __syncthreads();
#pragma unroll
    for (int j = 0; j < 4; ++j)
        Wt[(size_t)(n0 + ty + j * 8) * K + k0 + tx] = t[tx][ty + j * 8];
}

// ---------------------------------------------------------------------------
// QKV GEMM (m97 structure): A bf16 [8192][768], Bt bf16 [2304][768].
// 128x128 tile, BK=32, 4 waves 2x2, each wave 64x64 (4x4 fragments).
// global_load_lds w16 both operands; linear LDS [128][32].
// Epilogue: col<1536 -> qk[row][col]; else V transposed -> vt[b][h][dh][s].
// ---------------------------------------------------------------------------
__global__ __launch_bounds__(256) void gemm_qkv128(const short* __restrict__ A,
                                                   const short* __restrict__ Bt,
                                                   const float* __restrict__ bias,
                                                   short* __restrict__ qkw,
                                                   short* __restrict__ vtw) {
    const int K = D_MODEL;
    __shared__ short As[128][32];
    __shared__ short Bs[128][32];
    const int tid = threadIdx.x, lane = tid & 63, w = tid >> 6;
    const int wr = w >> 1, wc = w & 1;
    const int lo = lane & 15, hi = lane >> 4;
    const int m0 = blockIdx.y * 128, n0 = blockIdx.x * 128;
    const int lr = lane >> 2, lc = (lane & 3) * 8;

    floatx4 acc[4][4] = {};
    const short* Ag = A  + (size_t)(m0 + w * 16 + lr) * K + lc;
    const short* Bg = Bt + (size_t)(n0 + w * 16 + lr) * K + lc;

    for (int k0 = 0; k0 < K; k0 += 32) {
        __syncthreads();
        gload16(Ag + k0,                 &As[w * 16][0]);
        gload16(Ag + k0 + (size_t)64 * K, &As[64 + w * 16][0]);
        gload16(Bg + k0,                 &Bs[w * 16][0]);
        gload16(Bg + k0 + (size_t)64 * K, &Bs[64 + w * 16][0]);
        __syncthreads();
        short8 a[4], bf[4];
#pragma unroll
        for (int m = 0; m < 4; ++m) a[m] = *(const short8*)&As[wr * 64 + m * 16 + lo][hi * 8];
#pragma unroll
        for (int n = 0; n < 4; ++n) bf[n] = *(const short8*)&Bs[wc * 64 + n * 16 + lo][hi * 8];
#pragma unroll
        for (int m = 0; m < 4; ++m)
#pragma unroll
            for (int n = 0; n < 4; ++n)
                acc[m][n] = __builtin_amdgcn_mfma_f32_16x16x32_bf16(a[m], bf[n], acc[m][n], 0, 0, 0);
    }

#pragma unroll
    for (int m = 0; m < 4; ++m)
#pragma unroll
        for (int n = 0; n < 4; ++n) {
            int col  = n0 + wc * 64 + n * 16 + lo;
            int row0 = m0 + wr * 64 + m * 16 + hi * 4;
            float bv = bias[col];
            if (col < LDQK) {
#pragma unroll
                for (int r = 0; r < 4; ++r)
                    qkw[(size_t)(row0 + r) * LDQK + col] = f2bf(acc[m][n][r] + bv);
            } else {
                int vcol = col - LDQK;
                int hh = vcol >> 6, dh = vcol & 63;
                int bb = row0 >> 12, s = row0 & 4095;
                short tmp[4] = {f2bf(acc[m][n][0] + bv), f2bf(acc[m][n][1] + bv),
                                f2bf(acc[m][n][2] + bv), f2bf(acc[m][n][3] + bv)};
                *(short4v*)&vtw[(((size_t)bb * NHEAD + hh) * 64 + dh) * SEQ + s] = *(const short4v*)tmp;
            }
        }
}

// ---------------------------------------------------------------------------
// Out GEMM: A=y bf16 [8192][768], Bt=wt_out bf16 [768][768] -> fp32 + bias.
// ---------------------------------------------------------------------------
__global__ __launch_bounds__(256) void gemm_out128(const short* __restrict__ A,
                                                   const short* __restrict__ Bt,
                                                   const float* __restrict__ bias,
                                                   float* __restrict__ C) {
    const int K = D_MODEL, N = D_MODEL;
    __shared__ short As[128][32];
    __shared__ short Bs[128][32];
    const int tid = threadIdx.x, lane = tid & 63, w = tid >> 6;
    const int wr = w >> 1, wc = w & 1;
    const int lo = lane & 15, hi = lane >> 4;
    const int m0 = blockIdx.y * 128, n0 = blockIdx.x * 128;
    const int lr = lane >> 2, lc = (lane & 3) * 8;

    floatx4 acc[4][4] = {};
    const short* Ag = A  + (size_t)(m0 + w * 16 + lr) * K + lc;
    const short* Bg = Bt + (size_t)(n0 + w * 16 + lr) * K + lc;

    for (int k0 = 0; k0 < K; k0 += 32) {
        __syncthreads();
        gload16(Ag + k0,                 &As[w * 16][0]);
        gload16(Ag + k0 + (size_t)64 * K, &As[64 + w * 16][0]);
        gload16(Bg + k0,                 &Bs[w * 16][0]);
        gload16(Bg + k0 + (size_t)64 * K, &Bs[64 + w * 16][0]);
        __syncthreads();
        short8 a[4], bf[4];
#pragma unroll
        for (int m = 0; m < 4; ++m) a[m] = *(const short8*)&As[wr * 64 + m * 16 + lo][hi * 8];
#pragma unroll
        for (int n = 0; n < 4; ++n) bf[n] = *(const short8*)&Bs[wc * 64 + n * 16 + lo][hi * 8];
#pragma unroll
        for (int m = 0; m < 4; ++m)
#pragma unroll
            for (int n = 0; n < 4; ++n)
                acc[m][n] = __builtin_amdgcn_mfma_f32_16x16x32_bf16(a[m], bf[n], acc[m][n], 0, 0, 0);
    }

#pragma unroll
    for (int m = 0; m < 4; ++m)
#pragma unroll
        for (int n = 0; n < 4; ++n) {
            int col  = n0 + wc * 64 + n * 16 + lo;
            int row0 = m0 + wr * 64 + m * 16 + hi * 4;
            float bv = bias[col];
#pragma unroll
            for (int r = 0; r < 4; ++r)
                C[(size_t)(row0 + r) * N + col] = acc[m][n][r] + bv;
        }
}

// ---------------------------------------------------------------------------
// Flash attention (causal), swapped-QK^T, in-register softmax, paired q-tiles.
// Block = (pair i, h, b) processes q-tiles {63-i, i}: exactly 65 iterations
// per block -> perfectly balanced grid of 768 blocks.
// ---------------------------------------------------------------------------
__global__ __launch_bounds__(256) void attn_k(const short* __restrict__ qk,
                                              const short* __restrict__ vt,
                                              short* __restrict__ y) {
    const int ip = blockIdx.x, h = blockIdx.y, b = blockIdx.z;
    const int tid = threadIdx.x, lane = tid & 63, w = tid >> 6;
    const int lo = lane & 15, hi = lane >> 4;

    __shared__ alignas(16) short Ks[64 * 64];     // key*64 + (dblk^(key&7))*8
    __shared__ alignas(16) short Vs[64 * 64];     // dim*64 + (kblk^(dim&7))*8
    __shared__ alignas(16) short Ps[4 * 16 * 64]; // per-wave; 4-short blocks ^ (q&14)

    const short* qbase = qk + (size_t)b * SEQ * LDQK;
    const short* kbase = qbase + D_MODEL;
    const short* vbase = vt + ((size_t)b * NHEAD + h) * 64 * SEQ;

    const int skey = tid >> 2, sdc = tid & 3;
    const int sdim = tid >> 2, skg = tid & 3;

    for (int t = 0; t < 2; ++t) {
        const int qt = t ? ip : 63 - ip;
        const int q0 = qt * 64;

        short8 qf[2];
        {
            const short* qrow = qbase + (size_t)(q0 + w * 16 + lo) * LDQK + h * 64;
            qf[0] = *(const short8*)(qrow + hi * 8);
            qf[1] = *(const short8*)(qrow + 32 + hi * 8);
        }

        floatx4 o[4] = {};
        float mrun = -1e30f, lrun = 0.0f;

        short8 kpre[2], vpre[2];
        {
            const short* ksrc = kbase + (size_t)skey * LDQK + h * 64 + sdc * 16;
            kpre[0] = *(const short8*)ksrc;
            kpre[1] = *(const short8*)(ksrc + 8);
            const short* vsrc = vbase + (size_t)sdim * SEQ + skg * 16;
            vpre[0] = *(const short8*)vsrc;
            vpre[1] = *(const short8*)(vsrc + 8);
        }

        float sc4[4];
        for (int kb = 0; kb <= qt; ++kb) {
            __syncthreads();
            {
                int kb0 = sdc * 2;
                *(short8*)&Ks[skey * 64 + ((kb0    ) ^ (skey & 7)) * 8] = kpre[0];
                *(short8*)&Ks[skey * 64 + ((kb0 + 1) ^ (skey & 7)) * 8] = kpre[1];
                int vb0 = skg * 2;
                *(short8*)&Vs[sdim * 64 + ((vb0    ) ^ (sdim & 7)) * 8] = vpre[0];
                *(short8*)&Vs[sdim * 64 + ((vb0 + 1) ^ (sdim & 7)) * 8] = vpre[1];
            }
            __syncthreads();
            if (kb < qt) {  // prefetch next tile's K/V into registers
                int k0n = (kb + 1) * 64;
                const short* ksrc = kbase + (size_t)(k0n + skey) * LDQK + h * 64 + sdc * 16;
                kpre[0] = *(const short8*)ksrc;
                kpre[1] = *(const short8*)(ksrc + 8);
                const short* vsrc = vbase + (size_t)sdim * SEQ + k0n + skg * 16;
                vpre[0] = *(const short8*)vsrc;
                vpre[1] = *(const short8*)(vsrc + 8);
            }

            // S^T = K @ Q^T : lane holds S[key=c*16+hi*4+r][q=w*16+lo]
            floatx4 sT[4];
            __builtin_amdgcn_s_setprio(1);
#pragma unroll
            for (int c = 0; c < 4; ++c) {
                floatx4 acc = {};
#pragma unroll
                for (int kc = 0; kc < 2; ++kc) {
                    short8 kf = *(const short8*)&Ks[(c * 16 + lo) * 64 + ((kc * 4 + hi) ^ (lo & 7)) * 8];
                    acc = __builtin_amdgcn_mfma_f32_16x16x32_bf16(kf, qf[kc], acc, 0, 0, 0);
                }
                sT[c] = acc;
            }
            __builtin_amdgcn_s_setprio(0);

            // softmax in-register for q = w*16+lo
            float p[4][4];
            const bool diag = (kb == qt);
            const int qin = w * 16 + lo;
            float mx = -1e30f;
#pragma unroll
            for (int c = 0; c < 4; ++c)
#pragma unroll
                for (int r = 0; r < 4; ++r) {
                    float v = sT[c][r] * 0.125f;
                    if (diag && (c * 16 + hi * 4 + r) > qin) v = -1e30f;
                    p[c][r] = v;
                    mx = fmaxf(mx, v);
                }
            mx = fmaxf(mx, __shfl_xor(mx, 16, 64));
            mx = fmaxf(mx, __shfl_xor(mx, 32, 64));
            float mnew = fmaxf(mrun, mx);
            float sc = __expf(mrun - mnew);
            mrun = mnew;
            float rs = 0.0f;
#pragma unroll
            for (int c = 0; c < 4; ++c)
#pragma unroll
                for (int r = 0; r < 4; ++r) {
                    float e = __expf(p[c][r] - mnew);
                    p[c][r] = e;
                    rs += e;
                }
            rs += __shfl_xor(rs, 16, 64);
            rs += __shfl_xor(rs, 32, 64);
            lrun = lrun * sc + rs;

#pragma unroll
            for (int r = 0; r < 4; ++r) sc4[r] = __shfl(sc, hi * 4 + r, 16);
#pragma unroll
            for (int dc = 0; dc < 4; ++dc)
#pragma unroll
                for (int r = 0; r < 4; ++r) o[dc][r] *= sc4[r];

            // P^T -> wave-local LDS (packed u32, swizzled)
            unsigned* pw = (unsigned*)&Ps[w * 1024];
#pragma unroll
            for (int c = 0; c < 4; ++c)
#pragma unroll
                for (int rp = 0; rp < 2; ++rp) {
                    unsigned word = pack2(p[c][rp * 2], p[c][rp * 2 + 1]);
                    pw[(lo * 64 + (((c * 4 + hi) ^ (lo & 14)) * 4) + rp * 2) >> 1] = word;
                }
            asm volatile("s_waitcnt lgkmcnt(0)" ::: "memory");

            // O += P V
            __builtin_amdgcn_s_setprio(1);
#pragma unroll
            for (int kc = 0; kc < 2; ++kc) {
                short8 af = *(const short8*)&Ps[w * 1024 + lo * 64 + ((kc * 8 + hi * 2) ^ (lo & 14)) * 4];
#pragma unroll
                for (int dc = 0; dc < 4; ++dc) {
                    short8 vf = *(const short8*)&Vs[(dc * 16 + lo) * 64 + ((kc * 4 + hi) ^ (lo & 7)) * 8];
                    o[dc] = __builtin_amdgcn_mfma_f32_16x16x32_bf16(af, vf, o[dc], 0, 0, 0);
                }
            }
            __builtin_amdgcn_s_setprio(0);
        }

#pragma unroll
        for (int r = 0; r < 4; ++r) sc4[r] = __shfl(lrun, hi * 4 + r, 16);
#pragma unroll
        for (int r = 0; r < 4; ++r) {
            float inv = 1.0f / sc4[r];
            int row = q0 + w * 16 + hi * 4 + r;
            short* dst = y + ((size_t)b * SEQ + row) * D_MODEL + h * 64;
#pragma unroll
            for (int dc = 0; dc < 4; ++dc) dst[dc * 16 + lo] = f2bf(o[dc][r] * inv);
        }
    }
}

extern "C" void kernel_launch(void* const* d_in, const int* in_sizes, int n_in,
                              void* d_out, int out_size, void* d_ws, size_t ws_size,
                              hipStream_t stream) {
    (void)in_sizes; (void)n_in; (void)out_size; (void)ws_size;
    const float* x     = (const float*)d_in[0];
    const float* W_in  = (const float*)d_in[1];
    const float* b_in  = (const float*)d_in[2];
    const float* W_out = (const float*)d_in[3];
    const float* b_out = (const float*)d_in[4];
    float* out = (float*)d_out;

    const int M = NB * SEQ;  // 8192
    char* p = (char*)d_ws;
    short* xbf   = (short*)p; p += (size_t)M * D_MODEL * 2;
    short* wtin  = (short*)p; p += (size_t)3 * D_MODEL * D_MODEL * 2;
    short* wtout = (short*)p; p += (size_t)D_MODEL * D_MODEL * 2;
    short* qkw   = (short*)p; p += (size_t)M * LDQK * 2;
    short* vtw   = (short*)p; p += (size_t)NB * NHEAD * 64 * SEQ * 2;
    short* yw    = (short*)p;

    convert_bf16<<<dim3((unsigned)((size_t)M * D_MODEL / 8 / 256)), 256, 0, stream>>>(
        x, xbf, (size_t)M * D_MODEL);
    transpose_bf16<<<dim3(3 * D_MODEL / 32, D_MODEL / 32), dim3(32, 8), 0, stream>>>(
        W_in, wtin, D_MODEL, 3 * D_MODEL);
    transpose_bf16<<<dim3(D_MODEL / 32, D_MODEL / 32), dim3(32, 8), 0, stream>>>(
        W_out, wtout, D_MODEL, D_MODEL);
    gemm_qkv128<<<dim3(3 * D_MODEL / 128, M / 128), 256, 0, stream>>>(
        xbf, wtin, b_in, qkw, vtw);
    attn_k<<<dim3(SEQ / 128, NHEAD, NB), 256, 0, stream>>>(qkw, vtw, yw);
    gemm_out128<<<dim3(D_MODEL / 128, M / 128), 256, 0, stream>>>(yw, wtout, b_out, out);
}

// Round 5
// 194.561 us; speedup vs baseline: 2.9176x; 1.1137x over previous
//
#include <hip/hip_runtime.h>
#include <hip/hip_bf16.h>

// B=2, S=4096, D=768, H=12, d_head=64.
// convert x/W to bf16 (W transposed) -> 128^2 m97-style GEMM (global_load_lds)
// -> balanced flash attention (paired q-tiles, swapped QK^T, in-reg softmax,
//    exp2-folded, defer-max, cvt_pk packing) -> 128^2 out GEMM.

#define D_MODEL 768
#define SEQ 4096
#define NB 2
#define NHEAD 12
#define LDQK 1536

typedef __attribute__((ext_vector_type(8))) short short8;
typedef __attribute__((ext_vector_type(4))) short short4v;
typedef __attribute__((ext_vector_type(4))) float floatx4;

#define SM_C 0.18033688011112042f  /* 0.125 * log2(e) */

#if __has_builtin(__builtin_amdgcn_exp2f)
#define EXP2(x) __builtin_amdgcn_exp2f(x)
#else
#define EXP2(x) __expf((x) * 0.6931471805599453f)
#endif

__device__ inline short fb(float f) {             // single f32->bf16 (RNE)
    union { __hip_bfloat16 h; short s; } cv;
    cv.h = __float2bfloat16(f);
    return cv.s;
}
__device__ inline unsigned pk2(float a, float b) { // packed pair -> v_cvt_pk_bf16_f32
    float2 f; f.x = a; f.y = b;
    union { __hip_bfloat162 h; unsigned u; } cv;
    cv.h = __float22bfloat162_rn(f);
    return cv.u;
}
__device__ inline void gload16(const void* g, void* l) {
    __builtin_amdgcn_global_load_lds(
        (const __attribute__((address_space(1))) unsigned int*)g,
        (__attribute__((address_space(3))) unsigned int*)l, 16, 0, 0);
}

// ---------------------------------------------------------------------------
__global__ __launch_bounds__(256) void convert_bf16(const float* __restrict__ src,
                                                    short* __restrict__ dst, size_t n) {
    size_t i = ((size_t)blockIdx.x * 256 + threadIdx.x) * 8;
    if (i >= n) return;
    float4 f0 = *(const float4*)(src + i);
    float4 f1 = *(const float4*)(src + i + 4);
    uint4 u = {pk2(f0.x, f0.y), pk2(f0.z, f0.w), pk2(f1.x, f1.y), pk2(f1.z, f1.w)};
    *(uint4*)(dst + i) = u;
}

// W[K][N] fp32 -> Wt[N][K] bf16, 32x32 tiles. block (32,8).
__global__ __launch_bounds__(256) void transpose_bf16(const float* __restrict__ W,
                                                      short* __restrict__ Wt,
                                                      int K, int N) {
    __shared__ short t[32][33];
    const int n0 = blockIdx.x * 32, k0 = blockIdx.y * 32;
    const int tx = threadIdx.x, ty = threadIdx.y;
#pragma unroll
    for (int j = 0; j < 4; ++j)
        t[ty + j * 8][tx] = fb(W[(size_t)(k0 + ty + j * 8) * N + n0 + tx]);
    __syncthreads();
#pragma unroll
    for (int j = 0; j < 4; ++j)
        Wt[(size_t)(n0 + ty + j * 8) * K + k0 + tx] = t[tx][ty + j * 8];
}

// ---------------------------------------------------------------------------
// QKV GEMM (m97 structure): A bf16 [8192][768], Bt bf16 [2304][768].
// ---------------------------------------------------------------------------
__global__ __launch_bounds__(256) void gemm_qkv128(const short* __restrict__ A,
                                                   const short* __restrict__ Bt,
                                                   const float* __restrict__ bias,
                                                   short* __restrict__ qkw,
                                                   short* __restrict__ vtw) {
    const int K = D_MODEL;
    __shared__ short As[128][32];
    __shared__ short Bs[128][32];
    const int tid = threadIdx.x, lane = tid & 63, w = tid >> 6;
    const int wr = w >> 1, wc = w & 1;
    const int lo = lane & 15, hi = lane >> 4;
    const int m0 = blockIdx.y * 128, n0 = blockIdx.x * 128;
    const int lr = lane >> 2, lc = (lane & 3) * 8;

    floatx4 acc[4][4] = {};
    const short* Ag = A  + (size_t)(m0 + w * 16 + lr) * K + lc;
    const short* Bg = Bt + (size_t)(n0 + w * 16 + lr) * K + lc;

    for (int k0 = 0; k0 < K; k0 += 32) {
        __syncthreads();
        gload16(Ag + k0,                  &As[w * 16][0]);
        gload16(Ag + k0 + (size_t)64 * K, &As[64 + w * 16][0]);
        gload16(Bg + k0,                  &Bs[w * 16][0]);
        gload16(Bg + k0 + (size_t)64 * K, &Bs[64 + w * 16][0]);
        __syncthreads();
        short8 a[4], bf[4];
#pragma unroll
        for (int m = 0; m < 4; ++m) a[m] = *(const short8*)&As[wr * 64 + m * 16 + lo][hi * 8];
#pragma unroll
        for (int n = 0; n < 4; ++n) bf[n] = *(const short8*)&Bs[wc * 64 + n * 16 + lo][hi * 8];
#pragma unroll
        for (int m = 0; m < 4; ++m)
#pragma unroll
            for (int n = 0; n < 4; ++n)
                acc[m][n] = __builtin_amdgcn_mfma_f32_16x16x32_bf16(a[m], bf[n], acc[m][n], 0, 0, 0);
    }

#pragma unroll
    for (int m = 0; m < 4; ++m)
#pragma unroll
        for (int n = 0; n < 4; ++n) {
            int col  = n0 + wc * 64 + n * 16 + lo;
            int row0 = m0 + wr * 64 + m * 16 + hi * 4;
            float bv = bias[col];
            if (col < LDQK) {
#pragma unroll
                for (int r = 0; r < 4; ++r)
                    qkw[(size_t)(row0 + r) * LDQK + col] = fb(acc[m][n][r] + bv);
            } else {
                int vcol = col - LDQK;
                int hh = vcol >> 6, dh = vcol & 63;
                int bb = row0 >> 12, s = row0 & 4095;
                uint2 u = {pk2(acc[m][n][0] + bv, acc[m][n][1] + bv),
                           pk2(acc[m][n][2] + bv, acc[m][n][3] + bv)};
                *(uint2*)&vtw[(((size_t)bb * NHEAD + hh) * 64 + dh) * SEQ + s] = u;
            }
        }
}

// ---------------------------------------------------------------------------
__global__ __launch_bounds__(256) void gemm_out128(const short* __restrict__ A,
                                                   const short* __restrict__ Bt,
                                                   const float* __restrict__ bias,
                                                   float* __restrict__ C) {
    const int K = D_MODEL, N = D_MODEL;
    __shared__ short As[128][32];
    __shared__ short Bs[128][32];
    const int tid = threadIdx.x, lane = tid & 63, w = tid >> 6;
    const int wr = w >> 1, wc = w & 1;
    const int lo = lane & 15, hi = lane >> 4;
    const int m0 = blockIdx.y * 128, n0 = blockIdx.x * 128;
    const int lr = lane >> 2, lc = (lane & 3) * 8;

    floatx4 acc[4][4] = {};
    const short* Ag = A  + (size_t)(m0 + w * 16 + lr) * K + lc;
    const short* Bg = Bt + (size_t)(n0 + w * 16 + lr) * K + lc;

    for (int k0 = 0; k0 < K; k0 += 32) {
        __syncthreads();
        gload16(Ag + k0,                  &As[w * 16][0]);
        gload16(Ag + k0 + (size_t)64 * K, &As[64 + w * 16][0]);
        gload16(Bg + k0,                  &Bs[w * 16][0]);
        gload16(Bg + k0 + (size_t)64 * K, &Bs[64 + w * 16][0]);
        __syncthreads();
        short8 a[4], bf[4];
#pragma unroll
        for (int m = 0; m < 4; ++m) a[m] = *(const short8*)&As[wr * 64 + m * 16 + lo][hi * 8];
#pragma unroll
        for (int n = 0; n < 4; ++n) bf[n] = *(const short8*)&Bs[wc * 64 + n * 16 + lo][hi * 8];
#pragma unroll
        for (int m = 0; m < 4; ++m)
#pragma unroll
            for (int n = 0; n < 4; ++n)
                acc[m][n] = __builtin_amdgcn_mfma_f32_16x16x32_bf16(a[m], bf[n], acc[m][n], 0, 0, 0);
    }

#pragma unroll
    for (int m = 0; m < 4; ++m)
#pragma unroll
        for (int n = 0; n < 4; ++n) {
            int col  = n0 + wc * 64 + n * 16 + lo;
            int row0 = m0 + wr * 64 + m * 16 + hi * 4;
            float bv = bias[col];
#pragma unroll
            for (int r = 0; r < 4; ++r)
                C[(size_t)(row0 + r) * N + col] = acc[m][n][r] + bv;
        }
}

// ---------------------------------------------------------------------------
// Flash attention (causal), paired q-tiles {63-i, i}. Swapped QK^T, in-reg
// softmax with exp2 fold + defer-max, diagonal tile peeled, cvt_pk P-pack.
// ---------------------------------------------------------------------------
__global__ __launch_bounds__(256) void attn_k(const short* __restrict__ qk,
                                              const short* __restrict__ vt,
                                              short* __restrict__ y) {
    const int ip = blockIdx.x, h = blockIdx.y, b = blockIdx.z;
    const int tid = threadIdx.x, lane = tid & 63, w = tid >> 6;
    const int lo = lane & 15, hi = lane >> 4;

    __shared__ alignas(16) short Ks[64 * 64];     // key*64 + (dblk^(key&7))*8
    __shared__ alignas(16) short Vs[64 * 64];     // dim*64 + (kblk^(dim&7))*8
    __shared__ alignas(16) short Ps[4 * 16 * 64]; // per-wave; 4-short blocks ^ (q&14)

    const short* qbase = qk + (size_t)b * SEQ * LDQK;
    const short* kbase = qbase + D_MODEL;
    const short* vbase = vt + ((size_t)b * NHEAD + h) * 64 * SEQ;

    const int skey = tid >> 2, sdc = tid & 3;
    const int sdim = tid >> 2, skg = tid & 3;

    // loop-invariant LDS addresses
    short* kcommit0 = &Ks[skey * 64 + (((sdc * 2)    ) ^ (skey & 7)) * 8];
    short* kcommit1 = &Ks[skey * 64 + (((sdc * 2) + 1) ^ (skey & 7)) * 8];
    short* vcommit0 = &Vs[sdim * 64 + (((skg * 2)    ) ^ (sdim & 7)) * 8];
    short* vcommit1 = &Vs[sdim * 64 + (((skg * 2) + 1) ^ (sdim & 7)) * 8];
    unsigned* pwbase = (unsigned*)&Ps[w * 1024];

    for (int t = 0; t < 2; ++t) {
        const int qt = t ? ip : 63 - ip;
        const int q0 = qt * 64;

        short8 qf[2];
        {
            const short* qrow = qbase + (size_t)(q0 + w * 16 + lo) * LDQK + h * 64;
            qf[0] = *(const short8*)(qrow + hi * 8);
            qf[1] = *(const short8*)(qrow + 32 + hi * 8);
        }

        floatx4 o[4] = {};
        float mrun = -1e30f, mC = -1e28f, lrun = 0.0f;
        float sc4[4];

        const short* kptr = kbase + (size_t)skey * LDQK + h * 64 + sdc * 16;
        const short* vptr = vbase + (size_t)sdim * SEQ + skg * 16;
        short8 kpre[2], vpre[2];
        kpre[0] = *(const short8*)kptr;
        kpre[1] = *(const short8*)(kptr + 8);
        vpre[0] = *(const short8*)vptr;
        vpre[1] = *(const short8*)(vptr + 8);

        auto tile_body = [&](bool diag) {
            // S^T = K @ Q^T : lane holds S[key=c*16+hi*4+r][q=w*16+lo]
            floatx4 sT[4];
            __builtin_amdgcn_s_setprio(1);
#pragma unroll
            for (int c = 0; c < 4; ++c) {
                floatx4 acc = {};
#pragma unroll
                for (int kc = 0; kc < 2; ++kc) {
                    short8 kf = *(const short8*)&Ks[(c * 16 + lo) * 64 + ((kc * 4 + hi) ^ (lo & 7)) * 8];
                    acc = __builtin_amdgcn_mfma_f32_16x16x32_bf16(kf, qf[kc], acc, 0, 0, 0);
                }
                sT[c] = acc;
            }
            __builtin_amdgcn_s_setprio(0);

            const int qin = w * 16 + lo;
            if (diag) {
#pragma unroll
                for (int c = 0; c < 4; ++c)
#pragma unroll
                    for (int r = 0; r < 4; ++r)
                        if ((c * 16 + hi * 4 + r) > qin) sT[c][r] = -1e30f;
            }
            // row max (tree), then 2 shuffles
            float mc[4];
#pragma unroll
            for (int c = 0; c < 4; ++c)
                mc[c] = fmaxf(fmaxf(sT[c][0], sT[c][1]), fmaxf(sT[c][2], sT[c][3]));
            float mx = fmaxf(fmaxf(mc[0], mc[1]), fmaxf(mc[2], mc[3]));
            mx = fmaxf(mx, __shfl_xor(mx, 16, 64));
            mx = fmaxf(mx, __shfl_xor(mx, 32, 64));

            // defer-max: rescale only if some row grew by > 64 raw (= 8 scaled)
            float lsc = 1.0f;
            if (__any(mx - mrun > 64.0f)) {
                float mnew = fmaxf(mrun, mx);
                float sc = EXP2((mrun - mnew) * SM_C);
                mrun = mnew;
                mC = mnew * SM_C;
                lsc = sc;
#pragma unroll
                for (int r = 0; r < 4; ++r) sc4[r] = __shfl(sc, hi * 4 + r, 16);
#pragma unroll
                for (int dc = 0; dc < 4; ++dc)
#pragma unroll
                    for (int r = 0; r < 4; ++r) o[dc][r] *= sc4[r];
            }

            // p = exp2(s*C - mC), row-sum
            float p[4][4];
            float rs = 0.0f;
#pragma unroll
            for (int c = 0; c < 4; ++c)
#pragma unroll
                for (int r = 0; r < 4; ++r) {
                    float e = EXP2(__builtin_fmaf(sT[c][r], SM_C, -mC));
                    p[c][r] = e;
                    rs += e;
                }
            rs += __shfl_xor(rs, 16, 64);
            rs += __shfl_xor(rs, 32, 64);
            lrun = __builtin_fmaf(lrun, lsc, rs);

            // P^T -> wave-local LDS (cvt_pk pairs, 8B writes, swizzled)
#pragma unroll
            for (int c = 0; c < 4; ++c) {
                uint2 word = {pk2(p[c][0], p[c][1]), pk2(p[c][2], p[c][3])};
                *(uint2*)(pwbase + ((lo * 64 + (((c * 4 + hi) ^ (lo & 14)) * 4)) >> 1)) = word;
            }
            asm volatile("s_waitcnt lgkmcnt(0)" ::: "memory");

            // O += P V
            __builtin_amdgcn_s_setprio(1);
#pragma unroll
            for (int kc = 0; kc < 2; ++kc) {
                short8 af = *(const short8*)&Ps[w * 1024 + lo * 64 + ((kc * 8 + hi * 2) ^ (lo & 14)) * 4];
#pragma unroll
                for (int dc = 0; dc < 4; ++dc) {
                    short8 vf = *(const short8*)&Vs[(dc * 16 + lo) * 64 + ((kc * 4 + hi) ^ (lo & 7)) * 8];
                    o[dc] = __builtin_amdgcn_mfma_f32_16x16x32_bf16(af, vf, o[dc], 0, 0, 0);
                }
            }
            __builtin_amdgcn_s_setprio(0);
        };

        // main loop: non-diagonal tiles (mask-free), prefetch next
        for (int kb = 0; kb < qt; ++kb) {
            __syncthreads();
            *(short8*)kcommit0 = kpre[0];
            *(short8*)kcommit1 = kpre[1];
            *(short8*)vcommit0 = vpre[0];
            *(short8*)vcommit1 = vpre[1];
            __syncthreads();
            kptr += (size_t)64 * LDQK;
            vptr += 64;
            kpre[0] = *(const short8*)kptr;
            kpre[1] = *(const short8*)(kptr + 8);
            vpre[0] = *(const short8*)vptr;
            vpre[1] = *(const short8*)(vptr + 8);
            tile_body(false);
        }
        // diagonal tile
        __syncthreads();
        *(short8*)kcommit0 = kpre[0];
        *(short8*)kcommit1 = kpre[1];
        *(short8*)vcommit0 = vpre[0];
        *(short8*)vcommit1 = vpre[1];
        __syncthreads();
        tile_body(true);

        // epilogue
#pragma unroll
        for (int r = 0; r < 4; ++r) sc4[r] = __shfl(lrun, hi * 4 + r, 16);
#pragma unroll
        for (int r = 0; r < 4; ++r) {
            float inv = 1.0f / sc4[r];
            int row = q0 + w * 16 + hi * 4 + r;
            short* dst = y + ((size_t)b * SEQ + row) * D_MODEL + h * 64;
#pragma unroll
            for (int dc = 0; dc < 4; ++dc) dst[dc * 16 + lo] = fb(o[dc][r] * inv);
        }
    }
}

extern "C" void kernel_launch(void* const* d_in, const int* in_sizes, int n_in,
                              void* d_out, int out_size, void* d_ws, size_t ws_size,
                              hipStream_t stream) {
    (void)in_sizes; (void)n_in; (void)out_size; (void)ws_size;
    const float* x     = (const float*)d_in[0];
    const float* W_in  = (const float*)d_in[1];
    const float* b_in  = (const float*)d_in[2];
    const float* W_out = (const float*)d_in[3];
    const float* b_out = (const float*)d_in[4];
    float* out = (float*)d_out;

    const int M = NB * SEQ;  // 8192
    char* p = (char*)d_ws;
    short* xbf   = (short*)p; p += (size_t)M * D_MODEL * 2;
    short* wtin  = (short*)p; p += (size_t)3 * D_MODEL * D_MODEL * 2;
    short* wtout = (short*)p; p += (size_t)D_MODEL * D_MODEL * 2;
    short* qkw   = (short*)p; p += (size_t)M * LDQK * 2;
    short* vtw   = (short*)p; p += (size_t)NB * NHEAD * 64 * SEQ * 2;
    short* yw    = (short*)p;

    convert_bf16<<<dim3((unsigned)((size_t)M * D_MODEL / 8 / 256)), 256, 0, stream>>>(
        x, xbf, (size_t)M * D_MODEL);
    transpose_bf16<<<dim3(3 * D_MODEL / 32, D_MODEL / 32), dim3(32, 8), 0, stream>>>(
        W_in, wtin, D_MODEL, 3 * D_MODEL);
    transpose_bf16<<<dim3(D_MODEL / 32, D_MODEL / 32), dim3(32, 8), 0, stream>>>(
        W_out, wtout, D_MODEL, D_MODEL);
    gemm_qkv128<<<dim3(3 * D_MODEL / 128, M / 128), 256, 0, stream>>>(
        xbf, wtin, b_in, qkw, vtw);
    attn_k<<<dim3(SEQ / 128, NHEAD, NB), 256, 0, stream>>>(qkw, vtw, yw);
    gemm_out128<<<dim3(D_MODEL / 128, M / 128), 256, 0, stream>>>(yw, wtout, b_out, out);
}